// Round 3
// baseline (14847.725 us; speedup 1.0000x reference)
//
#include <hip/hip_runtime.h>
#include <stdint.h>

typedef unsigned short u16;
typedef __bf16 bf16x8 __attribute__((ext_vector_type(8)));
typedef float  f32x4  __attribute__((ext_vector_type(4)));

static __device__ __forceinline__ u16 f2bf(float x){
  uint32_t u = __float_as_uint(x);
  u += 0x7fffu + ((u >> 16) & 1u);   // RNE
  return (u16)(u >> 16);
}
static __device__ __forceinline__ float dot4(float4 a, float4 b){
  return a.x*b.x + a.y*b.y + a.z*b.z + a.w*b.w;
}
static __device__ __forceinline__ float ftanh(float x){
  float e = __expf(2.f*x);
  return 1.f - 2.f/(e + 1.f);
}
static __device__ __forceinline__ float fsigm(float x){
  return 1.f / (1.f + __expf(-x));
}

// ---------------- f32 -> bf16 convert (vectorized, grid-stride) ----------------
__global__ __launch_bounds__(256) void conv_bf16_k(const float* __restrict__ src,
                                                   u16* __restrict__ dst, int n4){
  int i = blockIdx.x * 256 + threadIdx.x;
  int stride = gridDim.x * 256;
  for (; i < n4; i += stride){
    float4 v = ((const float4*)src)[i];
    ushort4 o;
    o.x = f2bf(v.x); o.y = f2bf(v.y); o.z = f2bf(v.z); o.w = f2bf(v.w);
    ((ushort4*)dst)[i] = o;
  }
}

// ---------------- embedding gather + h0 copy ----------------
__global__ __launch_bounds__(128) void embed_k(const int* __restrict__ targets,
                                               const float* __restrict__ emb,
                                               const float* __restrict__ ench,
                                               float* __restrict__ xemb,
                                               float* __restrict__ h0){
  int blk = blockIdx.x;
  if (blk < 992){
    int t = blk >> 5, b = blk & 31;          // row m = t*32+b
    int tok = targets[b * 32 + t];
    const float4* src = (const float4*)(emb + (size_t)tok * 512);
    float4* dst = (float4*)(xemb + (size_t)blk * 512);
    dst[threadIdx.x] = src[threadIdx.x];
  } else {
    int i = (blk - 992) * 128 + threadIdx.x;
    ((float4*)h0)[i] = ((const float4*)ench)[i];
  }
}

// ---------------- generic f32 NT GEMM: C[m,n] = sum_k A[m,k]*B[n,k] + bias[n] ----------------
__global__ __launch_bounds__(256) void gemm_f32_k(const float* __restrict__ A,
                                                  const float* __restrict__ B,
                                                  const float* __restrict__ bias,
                                                  float* __restrict__ C,
                                                  int M, int K, int lda, int ldb, int ldc){
  __shared__ float As[16 * 72];
  __shared__ float Bs[16 * 72];
  int tid = threadIdx.x;
  int m0 = blockIdx.y * 64, n0 = blockIdx.x * 64;
  int tx = tid & 15, ty = tid >> 4;
  int lrow = tid >> 2, lk = (tid & 3) * 4;
  const float* Ap = A + (size_t)(m0 + lrow) * lda + lk;
  const float* Bp = B + (size_t)(n0 + lrow) * ldb + lk;
  bool avalid = (m0 + lrow) < M;
  float acc[4][4] = {};
  for (int k0 = 0; k0 < K; k0 += 16){
    float4 av = avalid ? *(const float4*)(Ap + k0) : float4{0.f,0.f,0.f,0.f};
    float4 bv = *(const float4*)(Bp + k0);
    __syncthreads();
    As[(lk+0)*72 + lrow] = av.x; As[(lk+1)*72 + lrow] = av.y;
    As[(lk+2)*72 + lrow] = av.z; As[(lk+3)*72 + lrow] = av.w;
    Bs[(lk+0)*72 + lrow] = bv.x; Bs[(lk+1)*72 + lrow] = bv.y;
    Bs[(lk+2)*72 + lrow] = bv.z; Bs[(lk+3)*72 + lrow] = bv.w;
    __syncthreads();
#pragma unroll
    for (int kk = 0; kk < 16; ++kk){
      float4 a = *(const float4*)&As[kk*72 + ty*4];
      float4 b = *(const float4*)&Bs[kk*72 + tx*4];
      float avv[4] = {a.x, a.y, a.z, a.w};
      float bvv[4] = {b.x, b.y, b.z, b.w};
#pragma unroll
      for (int i = 0; i < 4; ++i)
#pragma unroll
        for (int j = 0; j < 4; ++j)
          acc[i][j] = fmaf(avv[i], bvv[j], acc[i][j]);
    }
  }
  float4 bb = *(const float4*)(bias + n0 + tx*4);
#pragma unroll
  for (int i = 0; i < 4; ++i){
    int row = m0 + ty*4 + i;
    if (row < M){
      float4 o;
      o.x = acc[i][0] + bb.x; o.y = acc[i][1] + bb.y;
      o.z = acc[i][2] + bb.z; o.w = acc[i][3] + bb.w;
      *(float4*)(C + (size_t)row * ldc + n0 + tx*4) = o;
    }
  }
}

// ---------------- persistent phase-B kernel ----------------
// 256 blocks x 512 threads, 1 block/CU (trivially co-resident; no LDS pressure).
// Block bid owns: attn-proj rows k = bid*4+{0..3}; GRU units j = bid*4+{0..3}.
// Weights are re-read from global each step, but each block reads the SAME
// 112KB slice every step from the same CU -> L2-resident (3.6MB/XCD).
// Manual grid barrier: sense-reversal, device-scope atomics, bounded spin.
static __device__ __forceinline__ void gridbar(unsigned* bar, unsigned* gen,
                                               unsigned &mygen, int nblk){
  __syncthreads();
  if (threadIdx.x == 0){
    __threadfence();
    unsigned g = mygen;
    unsigned old = __hip_atomic_fetch_add(bar, 1u, __ATOMIC_ACQ_REL,
                                          __HIP_MEMORY_SCOPE_AGENT);
    if (old == (unsigned)(nblk - 1)){
      __hip_atomic_store(bar, 0u, __ATOMIC_RELAXED, __HIP_MEMORY_SCOPE_AGENT);
      __hip_atomic_fetch_add(gen, 1u, __ATOMIC_RELEASE, __HIP_MEMORY_SCOPE_AGENT);
    } else {
      int spins = 0;
      while (__hip_atomic_load(gen, __ATOMIC_ACQUIRE, __HIP_MEMORY_SCOPE_AGENT) <= g){
        __builtin_amdgcn_s_sleep(8);
        if (++spins > (1 << 15)) break;   // safety valve: never hang the container
      }
    }
  }
  __syncthreads();
  mygen++;
}

__global__ __launch_bounds__(512, 2) void persist_k(
    const float* __restrict__ enc, const float* __restrict__ W1,
    const float* __restrict__ W2, const float* __restrict__ Wih,
    const float* __restrict__ Whh, const float* __restrict__ bhh,
    const float* __restrict__ EP, const float* __restrict__ GIX,
    float* __restrict__ HBUF, float* __restrict__ HP,
    float* __restrict__ CTX, unsigned* __restrict__ BAR){
  __shared__ float sPart[8 * 50 + 64];   // attn wave partials + alphas
  int tid = threadIdx.x, bid = blockIdx.x;
  unsigned* bar = BAR;
  unsigned* gen = BAR + 32;              // separate cacheline
  unsigned mygen = 0;

  int q = tid & 7, dq = (tid >> 3) & 3, bq = tid >> 5;   // bq 0..15
  int b0 = bq * 2, b1 = b0 + 1;
  int lane31 = tid & 31;

  // constants cached in registers
  float2 w2r = *(const float2*)&W2[(tid & 511) * 2 < 1024 ? tid * 2 : 0];
  float bhhR[4][3];
#pragma unroll
  for (int jj = 0; jj < 4; ++jj){
    int j = bid * 4 + jj;
    bhhR[jj][0] = bhh[j]; bhhR[jj][1] = bhh[1024 + j]; bhhR[jj][2] = bhh[2048 + j];
  }

  for (int t = 0; t < 31; ++t){
    const float* h = HBUF + (size_t)t * 32768;
    // ---- load h slices for b0,b1 (reused by hp and GRU gh) ----
    float4 hA[8], hB[8];
    {
      const float4* h4 = (const float4*)h;
#pragma unroll
      for (int i = 0; i < 8; ++i){
        int f = q + 8*dq + 32*i;
        hA[i] = h4[b0*256 + f];
        hB[i] = h4[b1*256 + f];
      }
    }
    // ---- hp[b, k] for k = bid*4+kk ----
    {
      float a0[4], a1[4];
#pragma unroll
      for (int kk = 0; kk < 4; ++kk){
        int k = bid*4 + kk;
        const float4* wr = (const float4*)(W1 + (size_t)k*2048 + 1024);
        float s0 = 0.f, s1 = 0.f;
#pragma unroll
        for (int i = 0; i < 8; ++i){
          int f = q + 8*dq + 32*i;
          float4 w = wr[f];
          s0 += dot4(w, hA[i]); s1 += dot4(w, hB[i]);
        }
        a0[kk] = s0; a1[kk] = s1;
      }
#pragma unroll
      for (int kk = 0; kk < 4; ++kk)
        for (int o = 1; o < 32; o <<= 1){
          a0[kk] += __shfl_xor(a0[kk], o);
          a1[kk] += __shfl_xor(a1[kk], o);
        }
      if (lane31 == 0){
#pragma unroll
        for (int kk = 0; kk < 4; ++kk){
          HP[b0*1024 + bid*4 + kk] = a0[kk];
          HP[b1*1024 + bid*4 + kk] = a1[kk];
        }
      }
    }
    gridbar(bar, gen, mygen, 256);

    // ---- attention (blocks 0..31: block b) ----
    if (bid < 32){
      int b = bid;
      float2 hp2 = *(const float2*)&HP[b*1024 + tid*2];
      int lane = tid & 63, wv = tid >> 6;
      for (int s = 0; s < 50; ++s){
        float2 ep2 = *(const float2*)&EP[(size_t)(b*50 + s)*1024 + tid*2];
        float v = ftanh(ep2.x + hp2.x) * w2r.x + ftanh(ep2.y + hp2.y) * w2r.y;
        for (int o = 32; o; o >>= 1) v += __shfl_xor(v, o);
        if (lane == 0) sPart[s*8 + wv] = v;
      }
      __syncthreads();
      if (tid < 64){
        float e = -1e30f;
        if (tid < 50){
          e = 0.f;
#pragma unroll
          for (int p = 0; p < 8; ++p) e += sPart[tid*8 + p];
        }
        float mx = e;
        for (int o = 32; o; o >>= 1) mx = fmaxf(mx, __shfl_xor(mx, o));
        float ex = (tid < 50) ? __expf(e - mx) : 0.f;
        float sm = ex;
        for (int o = 32; o; o >>= 1) sm += __shfl_xor(sm, o);
        if (tid < 50) sPart[400 + tid] = ex / sm;
      }
      __syncthreads();
      float cx = 0.f, cy = 0.f;
      const float* encb = enc + (size_t)b * 51200 + tid*2;
      for (int s = 0; s < 50; ++s){
        float a = sPart[400 + s];
        float2 ev = *(const float2*)&encb[s*1024];
        cx = fmaf(a, ev.x, cx); cy = fmaf(a, ev.y, cy);
      }
      *(float2*)&CTX[b*1024 + tid*2] = float2{cx, cy};
    }
    gridbar(bar, gen, mygen, 256);

    // ---- GRU for j = bid*4+{0..3} ----
    float4 cA[8], cB[8];
    {
      const float4* c4 = (const float4*)CTX;
#pragma unroll
      for (int i = 0; i < 8; ++i){
        int f = q + 8*dq + 32*i;
        cA[i] = c4[b0*256 + f];
        cB[i] = c4[b1*256 + f];
      }
    }
#pragma unroll
    for (int jj = 0; jj < 4; ++jj){
      int j = bid*4 + jj;
      const float4* wir = (const float4*)(Wih + (size_t)j*1536 + 512);
      const float4* wiz = (const float4*)(Wih + (size_t)(1024 + j)*1536 + 512);
      const float4* win = (const float4*)(Wih + (size_t)(2048 + j)*1536 + 512);
      const float4* vhr = (const float4*)(Whh + (size_t)j*1024);
      const float4* vhz = (const float4*)(Whh + (size_t)(1024 + j)*1024);
      const float4* vhn = (const float4*)(Whh + (size_t)(2048 + j)*1024);
      float air0=0, air1=0, aiz0=0, aiz1=0, ain0=0, ain1=0;
      float bhr0=0, bhr1=0, bhz0=0, bhz1=0, bhn0=0, bhn1=0;
#pragma unroll
      for (int i = 0; i < 8; ++i){
        int f = q + 8*dq + 32*i;
        float4 w;
        w = wir[f]; air0 += dot4(w, cA[i]); air1 += dot4(w, cB[i]);
        w = wiz[f]; aiz0 += dot4(w, cA[i]); aiz1 += dot4(w, cB[i]);
        w = win[f]; ain0 += dot4(w, cA[i]); ain1 += dot4(w, cB[i]);
        w = vhr[f]; bhr0 += dot4(w, hA[i]); bhr1 += dot4(w, hB[i]);
        w = vhz[f]; bhz0 += dot4(w, hA[i]); bhz1 += dot4(w, hB[i]);
        w = vhn[f]; bhn0 += dot4(w, hA[i]); bhn1 += dot4(w, hB[i]);
      }
      for (int o = 1; o < 32; o <<= 1){
        air0 += __shfl_xor(air0, o); air1 += __shfl_xor(air1, o);
        aiz0 += __shfl_xor(aiz0, o); aiz1 += __shfl_xor(aiz1, o);
        ain0 += __shfl_xor(ain0, o); ain1 += __shfl_xor(ain1, o);
        bhr0 += __shfl_xor(bhr0, o); bhr1 += __shfl_xor(bhr1, o);
        bhz0 += __shfl_xor(bhz0, o); bhz1 += __shfl_xor(bhz1, o);
        bhn0 += __shfl_xor(bhn0, o); bhn1 += __shfl_xor(bhn1, o);
      }
      if (lane31 == 0){
        float* hout = HBUF + (size_t)(t+1)*32768;
#pragma unroll
        for (int bb = 0; bb < 2; ++bb){
          int b = (bb == 0) ? b0 : b1;
          float ai_r = bb ? air1 : air0, ai_z = bb ? aiz1 : aiz0, ai_n = bb ? ain1 : ain0;
          float ah_r = bb ? bhr1 : bhr0, ah_z = bb ? bhz1 : bhz0, ah_n = bb ? bhn1 : bhn0;
          const float* gix = GIX + ((size_t)t*32 + b)*3072;
          float ir  = ai_r + gix[j];
          float iz  = ai_z + gix[1024 + j];
          float in_ = ai_n + gix[2048 + j];
          float hr_ = ah_r + bhhR[jj][0];
          float hz_ = ah_z + bhhR[jj][1];
          float hn_ = ah_n + bhhR[jj][2];
          float r = fsigm(ir + hr_);
          float z = fsigm(iz + hz_);
          float n = ftanh(in_ + r * hn_);
          float hv = h[b*1024 + j];
          hout[b*1024 + j] = (1.f - z)*n + z*hv;
        }
      }
    }
    gridbar(bar, gen, mygen, 256);
  }
}

// ---------------- logits GEMM (bf16 MFMA) ----------------
__global__ __launch_bounds__(256) void logits_k(const u16* __restrict__ Abf,
                                                const u16* __restrict__ Wbf,
                                                const float* __restrict__ bout,
                                                float* __restrict__ out){
  __shared__ u16 As[64 * 40];
  int tid = threadIdx.x, lane = tid & 63, w = tid >> 6;
  int n0 = blockIdx.x * 64, m0 = blockIdx.y * 64;
  int lr = tid >> 2, lk = (tid & 3) * 8;
  int r16 = lane & 15, kq = lane >> 4;
  bool avalid = (m0 + lr) < 992;
  const uint4* Ap = (const uint4*)(Abf + (size_t)(m0 + lr) * 1024 + lk);
  const uint4* Wp = (const uint4*)(Wbf + (size_t)(n0 + w * 16 + r16) * 1024 + kq * 8);
  f32x4 acc0 = {0.f,0.f,0.f,0.f}, acc1 = {0.f,0.f,0.f,0.f};
  f32x4 acc2 = {0.f,0.f,0.f,0.f}, acc3 = {0.f,0.f,0.f,0.f};
  for (int k0 = 0; k0 < 1024; k0 += 32){
    uint4 a4 = avalid ? Ap[k0 >> 3] : uint4{0,0,0,0};
    uint4 b4 = Wp[k0 >> 3];
    __syncthreads();
    *(uint4*)&As[lr * 40 + lk] = a4;
    __syncthreads();
    bf16x8 bfr = __builtin_bit_cast(bf16x8, b4);
    bf16x8 a0 = __builtin_bit_cast(bf16x8, *(const uint4*)&As[( 0 + r16) * 40 + kq * 8]);
    acc0 = __builtin_amdgcn_mfma_f32_16x16x32_bf16(a0, bfr, acc0, 0, 0, 0);
    bf16x8 a1 = __builtin_bit_cast(bf16x8, *(const uint4*)&As[(16 + r16) * 40 + kq * 8]);
    acc1 = __builtin_amdgcn_mfma_f32_16x16x32_bf16(a1, bfr, acc1, 0, 0, 0);
    bf16x8 a2 = __builtin_bit_cast(bf16x8, *(const uint4*)&As[(32 + r16) * 40 + kq * 8]);
    acc2 = __builtin_amdgcn_mfma_f32_16x16x32_bf16(a2, bfr, acc2, 0, 0, 0);
    bf16x8 a3 = __builtin_bit_cast(bf16x8, *(const uint4*)&As[(48 + r16) * 40 + kq * 8]);
    acc3 = __builtin_amdgcn_mfma_f32_16x16x32_bf16(a3, bfr, acc3, 0, 0, 0);
  }
  int n = n0 + w * 16 + r16;
  float bo = bout[n];
#define STORE_MS(MS, ACC)                                                        \
  {                                                                              \
    _Pragma("unroll")                                                            \
    for (int reg = 0; reg < 4; ++reg){                                           \
      int m = m0 + MS * 16 + kq * 4 + reg;                                       \
      if (m < 992){                                                              \
        int tt = m >> 5, bb = m & 31;                                            \
        out[(size_t)(bb * 31 + tt) * 32000 + n] = ACC[reg] + bo;                 \
      }                                                                          \
    }                                                                            \
  }
  STORE_MS(0, acc0) STORE_MS(1, acc1) STORE_MS(2, acc2) STORE_MS(3, acc3)
#undef STORE_MS
}

// ---------------- row-wise log_softmax over V=32000, in-place on d_out ----------------
__global__ __launch_bounds__(256) void lsm_k(float* __restrict__ out){
  __shared__ float red[4];
  __shared__ float red2[4];
  int row = blockIdx.x, tid = threadIdx.x, w = tid >> 6;
  float* p = out + (size_t)row * 32000;
  const float4* p4 = (const float4*)p;
  float m = -1e30f;
  for (int i = tid; i < 8000; i += 256){
    float4 v = p4[i];
    m = fmaxf(m, fmaxf(fmaxf(v.x, v.y), fmaxf(v.z, v.w)));
  }
  for (int off = 32; off; off >>= 1) m = fmaxf(m, __shfl_xor(m, off));
  if ((tid & 63) == 0) red[w] = m;
  __syncthreads();
  m = fmaxf(fmaxf(red[0], red[1]), fmaxf(red[2], red[3]));
  float s = 0.f;
  for (int i = tid; i < 8000; i += 256){
    float4 v = p4[i];
    s += __expf(v.x - m) + __expf(v.y - m) + __expf(v.z - m) + __expf(v.w - m);
  }
  for (int off = 32; off; off >>= 1) s += __shfl_xor(s, off);
  if ((tid & 63) == 0) red2[w] = s;
  __syncthreads();
  s = red2[0] + red2[1] + red2[2] + red2[3];
  float lse = m + __logf(s);
  for (int i = tid; i < 8000; i += 256){
    float4 v = p4[i];
    v.x -= lse; v.y -= lse; v.z -= lse; v.w -= lse;
    ((float4*)p)[i] = v;
  }
}

extern "C" void kernel_launch(void* const* d_in, const int* in_sizes, int n_in,
                              void* d_out, int out_size, void* d_ws, size_t ws_size,
                              hipStream_t stream){
  const float* enc  = (const float*)d_in[0];
  const float* ench = (const float*)d_in[1];
  const int*   tgt  = (const int*)d_in[2];
  const float* emb  = (const float*)d_in[3];
  const float* W1   = (const float*)d_in[4];
  const float* b1   = (const float*)d_in[5];
  const float* W2   = (const float*)d_in[6];
  const float* Wih  = (const float*)d_in[7];
  const float* bih  = (const float*)d_in[8];
  const float* Whh  = (const float*)d_in[9];
  const float* bhh  = (const float*)d_in[10];
  const float* Wout = (const float*)d_in[11];
  const float* bout = (const float*)d_in[12];
  float* out = (float*)d_out;

  char* ws = (char*)d_ws;
  size_t off = 0;
  auto alloc = [&](size_t bytes)->char*{
    char* p = ws + off;
    off += (bytes + 255) & ~(size_t)255;
    return p;
  };
  float* EP   = (float*)alloc((size_t)1600 * 1024 * 4);
  float* GIX  = (float*)alloc((size_t)992 * 3072 * 4);
  float* XEMB = (float*)alloc((size_t)992 * 512 * 4);
  float* HBUF = (float*)alloc((size_t)32 * 32 * 1024 * 4);
  float* HP   = (float*)alloc((size_t)32 * 1024 * 4);
  float* CTX  = (float*)alloc((size_t)32 * 1024 * 4);
  u16*   WBF  = (u16*)alloc((size_t)32000 * 1024 * 2);
  u16*   ABF  = (u16*)alloc((size_t)992 * 1024 * 2);
  unsigned* BAR = (unsigned*)alloc(256);
  (void)ws_size; (void)in_sizes; (void)n_in; (void)out_size;

  // Phase A (parallel pre-work)
  conv_bf16_k<<<2048, 256, 0, stream>>>(Wout, WBF, 32000 * 1024 / 4);
  embed_k<<<1056, 128, 0, stream>>>(tgt, emb, ench, XEMB, HBUF);
  gemm_f32_k<<<dim3(16, 25), 256, 0, stream>>>(enc, W1, b1, EP, 1600, 1024, 1024, 2048, 1024);
  gemm_f32_k<<<dim3(48, 16), 256, 0, stream>>>(XEMB, Wih, bih, GIX, 992, 512, 512, 1536, 3072);

  // Phase B: persistent kernel (plain launch, 1 block/CU), manual grid barrier
  hipMemsetAsync(BAR, 0, 256, stream);
  persist_k<<<256, 512, 0, stream>>>(enc, W1, W2, Wih, Whh, bhh,
                                     EP, GIX, HBUF, HP, CTX, BAR);

  // Phase C (deferred output projection + log_softmax)
  conv_bf16_k<<<1024, 256, 0, stream>>>(HBUF + 32768, ABF, 992 * 1024 / 4);
  logits_k<<<dim3(500, 16), 256, 0, stream>>>(ABF, WBF, bout, out);
  lsm_k<<<992, 256, 0, stream>>>(out);
}

// Round 8
// 7730.713 us; speedup vs baseline: 1.9206x; 1.9206x over previous
//
#include <hip/hip_runtime.h>
#include <stdint.h>

typedef unsigned short u16;
typedef __bf16 bf16x8 __attribute__((ext_vector_type(8)));
typedef float  f32x4  __attribute__((ext_vector_type(4)));

static __device__ __forceinline__ u16 f2bf(float x){
  uint32_t u = __float_as_uint(x);
  u += 0x7fffu + ((u >> 16) & 1u);   // RNE
  return (u16)(u >> 16);
}
static __device__ __forceinline__ float dot4(float4 a, float4 b){
  return a.x*b.x + a.y*b.y + a.z*b.z + a.w*b.w;
}
static __device__ __forceinline__ float ftanh(float x){
  float e = __expf(2.f*x);
  return 1.f - 2.f/(e + 1.f);
}
static __device__ __forceinline__ float fsigm(float x){
  return 1.f / (1.f + __expf(-x));
}

// ---------------- f32 -> bf16 convert (vectorized, grid-stride) ----------------
__global__ __launch_bounds__(256) void conv_bf16_k(const float* __restrict__ src,
                                                   u16* __restrict__ dst, int n4){
  int i = blockIdx.x * 256 + threadIdx.x;
  int stride = gridDim.x * 256;
  for (; i < n4; i += stride){
    float4 v = ((const float4*)src)[i];
    ushort4 o;
    o.x = f2bf(v.x); o.y = f2bf(v.y); o.z = f2bf(v.z); o.w = f2bf(v.w);
    ((ushort4*)dst)[i] = o;
  }
}

// ---------------- embedding gather + h0 copy ----------------
__global__ __launch_bounds__(128) void embed_k(const int* __restrict__ targets,
                                               const float* __restrict__ emb,
                                               const float* __restrict__ ench,
                                               float* __restrict__ xemb,
                                               float* __restrict__ h0){
  int blk = blockIdx.x;
  if (blk < 992){
    int t = blk >> 5, b = blk & 31;          // row m = t*32+b
    int tok = targets[b * 32 + t];
    const float4* src = (const float4*)(emb + (size_t)tok * 512);
    float4* dst = (float4*)(xemb + (size_t)blk * 512);
    dst[threadIdx.x] = src[threadIdx.x];
  } else {
    int i = (blk - 992) * 128 + threadIdx.x;
    ((float4*)h0)[i] = ((const float4*)ench)[i];
  }
}

// ---------------- generic f32 NT GEMM: C[m,n] = sum_k A[m,k]*B[n,k] + bias[n] ----------------
__global__ __launch_bounds__(256) void gemm_f32_k(const float* __restrict__ A,
                                                  const float* __restrict__ B,
                                                  const float* __restrict__ bias,
                                                  float* __restrict__ C,
                                                  int M, int K, int lda, int ldb, int ldc){
  __shared__ float As[16 * 72];
  __shared__ float Bs[16 * 72];
  int tid = threadIdx.x;
  int m0 = blockIdx.y * 64, n0 = blockIdx.x * 64;
  int tx = tid & 15, ty = tid >> 4;
  int lrow = tid >> 2, lk = (tid & 3) * 4;
  const float* Ap = A + (size_t)(m0 + lrow) * lda + lk;
  const float* Bp = B + (size_t)(n0 + lrow) * ldb + lk;
  bool avalid = (m0 + lrow) < M;
  float acc[4][4] = {};
  for (int k0 = 0; k0 < K; k0 += 16){
    float4 av = avalid ? *(const float4*)(Ap + k0) : float4{0.f,0.f,0.f,0.f};
    float4 bv = *(const float4*)(Bp + k0);
    __syncthreads();
    As[(lk+0)*72 + lrow] = av.x; As[(lk+1)*72 + lrow] = av.y;
    As[(lk+2)*72 + lrow] = av.z; As[(lk+3)*72 + lrow] = av.w;
    Bs[(lk+0)*72 + lrow] = bv.x; Bs[(lk+1)*72 + lrow] = bv.y;
    Bs[(lk+2)*72 + lrow] = bv.z; Bs[(lk+3)*72 + lrow] = bv.w;
    __syncthreads();
#pragma unroll
    for (int kk = 0; kk < 16; ++kk){
      float4 a = *(const float4*)&As[kk*72 + ty*4];
      float4 b = *(const float4*)&Bs[kk*72 + tx*4];
      float avv[4] = {a.x, a.y, a.z, a.w};
      float bvv[4] = {b.x, b.y, b.z, b.w};
#pragma unroll
      for (int i = 0; i < 4; ++i)
#pragma unroll
        for (int j = 0; j < 4; ++j)
          acc[i][j] = fmaf(avv[i], bvv[j], acc[i][j]);
    }
  }
  float4 bb = *(const float4*)(bias + n0 + tx*4);
#pragma unroll
  for (int i = 0; i < 4; ++i){
    int row = m0 + ty*4 + i;
    if (row < M){
      float4 o;
      o.x = acc[i][0] + bb.x; o.y = acc[i][1] + bb.y;
      o.z = acc[i][2] + bb.z; o.w = acc[i][3] + bb.w;
      *(float4*)(C + (size_t)row * ldc + n0 + tx*4) = o;
    }
  }
}

// ---------------- manual grid barrier ----------------
// Arrival: RELEASE fetch_add (writes back dirty L2 once).
// Spin: RELAXED loads (coherence-point reads; no per-iteration L2 invalidate).
// After wake: one __threadfence (acquire side -> invalidate caches once).
static __device__ __forceinline__ void gridbar(unsigned* bar, unsigned* gen,
                                               unsigned &mygen, int nblk){
  __syncthreads();
  if (threadIdx.x == 0){
    unsigned g = mygen;
    unsigned old = __hip_atomic_fetch_add(bar, 1u, __ATOMIC_RELEASE,
                                          __HIP_MEMORY_SCOPE_AGENT);
    if (old == (unsigned)(nblk - 1)){
      __hip_atomic_store(bar, 0u, __ATOMIC_RELAXED, __HIP_MEMORY_SCOPE_AGENT);
      __hip_atomic_fetch_add(gen, 1u, __ATOMIC_RELEASE, __HIP_MEMORY_SCOPE_AGENT);
    } else {
      int spins = 0;
      while (__hip_atomic_load(gen, __ATOMIC_RELAXED,
                               __HIP_MEMORY_SCOPE_AGENT) <= g){
        __builtin_amdgcn_s_sleep(2);
        if (++spins > (1 << 20)) break;   // safety valve: never hang
      }
    }
  }
  __threadfence();       // acquire: invalidate caches once, see remote writes
  __syncthreads();
  mygen++;
}

// ---------------- persistent phase-B kernel ----------------
// 512 blocks x 256 threads, exactly 2 blocks/CU (58KB static LDS + <=128 VGPR).
// Block bid owns attn-proj rows k = bid*2+{0,1} and GRU units j = bid*2+{0,1}.
// All 14 owned weight rows (56KB) live in LDS for all 31 steps -> weights are
// fetched from HBM exactly once; barriers only cost activation re-reads.
__global__ __launch_bounds__(256, 2) void persist_k(
    const float* __restrict__ enc, const float* __restrict__ W1,
    const float* __restrict__ W2, const float* __restrict__ Wih,
    const float* __restrict__ Whh, const float* __restrict__ bhh,
    const float* __restrict__ EP, const float* __restrict__ GIX,
    float* __restrict__ HBUF, float* __restrict__ HP,
    float* __restrict__ CTX, unsigned* __restrict__ BAR){
  __shared__ float sW1h[2][1024];   // attn-proj rows (h-part of W1)
  __shared__ float sWih[6][1024];   // rr = gate*2+jj, ctx-cols of W_ih
  __shared__ float sWhh[6][1024];   // rr = gate*2+jj
  __shared__ float sScr[384];       // attn wave partials / GRU dump
  __shared__ float sA[64];
  int tid = threadIdx.x, bid = blockIdx.x;
  unsigned* bar = BAR;
  unsigned* gen = BAR + 32;
  unsigned mygen = 0;

  // ---- one-time weight preload into LDS ----
  {
    int c = tid * 4;
#pragma unroll
    for (int kk = 0; kk < 2; ++kk)
      *(float4*)&sW1h[kk][c] =
          *(const float4*)&W1[(size_t)(bid*2 + kk)*2048 + 1024 + c];
#pragma unroll
    for (int rr = 0; rr < 6; ++rr){
      int jj = rr & 1, g = rr >> 1;
      *(float4*)&sWih[rr][c] =
          *(const float4*)&Wih[(size_t)(g*1024 + bid*2 + jj)*1536 + 512 + c];
      *(float4*)&sWhh[rr][c] =
          *(const float4*)&Whh[(size_t)(g*1024 + bid*2 + jj)*1024 + c];
    }
  }
  __syncthreads();

  int lane = tid & 31, grp = tid >> 5;   // 8 groups of 32 lanes

  for (int t = 0; t < 31; ++t){
    const float* h = HBUF + (size_t)t * 32768;
    float* hout = HBUF + (size_t)(t + 1) * 32768;

    // ---- hp[b,k] = h[b,:] . W1h[k,:]  (group grp: batches grp*4..+3) ----
    {
      float a[4][2] = {};
      for (int i = 0; i < 8; ++i){
        int f = (lane + 32*i) * 4;
        float4 w0 = *(float4*)&sW1h[0][f];
        float4 w1 = *(float4*)&sW1h[1][f];
#pragma unroll
        for (int bb = 0; bb < 4; ++bb){
          float4 hv = *(const float4*)&h[(grp*4 + bb)*1024 + f];
          a[bb][0] += dot4(hv, w0);
          a[bb][1] += dot4(hv, w1);
        }
      }
#pragma unroll
      for (int bb = 0; bb < 4; ++bb)
#pragma unroll
        for (int kk = 0; kk < 2; ++kk)
          for (int o = 1; o < 32; o <<= 1)
            a[bb][kk] += __shfl_xor(a[bb][kk], o);
      if (lane == 0){
#pragma unroll
        for (int bb = 0; bb < 4; ++bb){
          HP[(grp*4 + bb)*1024 + bid*2 + 0] = a[bb][0];
          HP[(grp*4 + bb)*1024 + bid*2 + 1] = a[bb][1];
        }
      }
    }
    gridbar(bar, gen, mygen, 512);

    // ---- attention (blocks 0..31: block handles batch b = bid) ----
    if (bid < 32){
      int b = bid;
      float4 hp4 = *(const float4*)&HP[b*1024 + tid*4];
      float4 w2v = *(const float4*)&W2[tid*4];
      int lane64 = tid & 63, wv = tid >> 6;
      for (int s = 0; s < 50; ++s){
        float4 ep4 = *(const float4*)&EP[(size_t)(b*50 + s)*1024 + tid*4];
        float v = ftanh(ep4.x + hp4.x)*w2v.x + ftanh(ep4.y + hp4.y)*w2v.y
                + ftanh(ep4.z + hp4.z)*w2v.z + ftanh(ep4.w + hp4.w)*w2v.w;
        for (int o = 32; o; o >>= 1) v += __shfl_xor(v, o);
        if (lane64 == 0) sScr[s*4 + wv] = v;
      }
      __syncthreads();
      if (tid < 64){
        float e = -1e30f;
        if (tid < 50)
          e = sScr[tid*4] + sScr[tid*4+1] + sScr[tid*4+2] + sScr[tid*4+3];
        float mx = e;
        for (int o = 32; o; o >>= 1) mx = fmaxf(mx, __shfl_xor(mx, o));
        float ex = (tid < 50) ? __expf(e - mx) : 0.f;
        float sm = ex;
        for (int o = 32; o; o >>= 1) sm += __shfl_xor(sm, o);
        if (tid < 50) sA[tid] = ex / sm;
      }
      __syncthreads();
      float4 c = {0.f,0.f,0.f,0.f};
      const float* encb = enc + (size_t)b * 51200 + tid*4;
      for (int s = 0; s < 50; ++s){
        float a = sA[s];
        float4 ev = *(const float4*)&encb[s*1024];
        c.x = fmaf(a, ev.x, c.x); c.y = fmaf(a, ev.y, c.y);
        c.z = fmaf(a, ev.z, c.z); c.w = fmaf(a, ev.w, c.w);
      }
      *(float4*)&CTX[b*1024 + tid*4] = c;
    }
    gridbar(bar, gen, mygen, 512);

    // ---- GRU: 2 passes (jj = 0,1), 24 accumulators each ----
#pragma unroll
    for (int jj = 0; jj < 2; ++jj){
      float aI[4][3] = {}, aH[4][3] = {};
      for (int i = 0; i < 8; ++i){
        int f = (lane + 32*i) * 4;
        float4 wI0 = *(float4*)&sWih[0*2+jj][f];
        float4 wI1 = *(float4*)&sWih[1*2+jj][f];
        float4 wI2 = *(float4*)&sWih[2*2+jj][f];
        float4 wH0 = *(float4*)&sWhh[0*2+jj][f];
        float4 wH1 = *(float4*)&sWhh[1*2+jj][f];
        float4 wH2 = *(float4*)&sWhh[2*2+jj][f];
#pragma unroll
        for (int bb = 0; bb < 4; ++bb){
          float4 cv = *(const float4*)&CTX[(grp*4 + bb)*1024 + f];
          float4 hv = *(const float4*)&h[(grp*4 + bb)*1024 + f];
          aI[bb][0] += dot4(cv, wI0); aI[bb][1] += dot4(cv, wI1); aI[bb][2] += dot4(cv, wI2);
          aH[bb][0] += dot4(hv, wH0); aH[bb][1] += dot4(hv, wH1); aH[bb][2] += dot4(hv, wH2);
        }
      }
#pragma unroll
      for (int bb = 0; bb < 4; ++bb)
#pragma unroll
        for (int g = 0; g < 3; ++g)
          for (int o = 1; o < 32; o <<= 1){
            aI[bb][g] += __shfl_xor(aI[bb][g], o);
            aH[bb][g] += __shfl_xor(aH[bb][g], o);
          }
      if (lane == 0){
#pragma unroll
        for (int bb = 0; bb < 4; ++bb)
#pragma unroll
          for (int g = 0; g < 3; ++g){
            sScr[grp*48 + bb*12 + (g*2 + jj)*2 + 0] = aI[bb][g];
            sScr[grp*48 + bb*12 + (g*2 + jj)*2 + 1] = aH[bb][g];
          }
      }
    }
    __syncthreads();
    if (tid < 64){
      int b = tid & 31, jj = tid >> 5;
      int g8 = b >> 2, bb = b & 3;
      int j = bid*2 + jj;
      const float* gx = GIX + ((size_t)t*32 + b)*3072;
      float Ir = sScr[g8*48 + bb*12 + (0*2+jj)*2 + 0] + gx[j];
      float Hr = sScr[g8*48 + bb*12 + (0*2+jj)*2 + 1] + bhh[j];
      float Iz = sScr[g8*48 + bb*12 + (1*2+jj)*2 + 0] + gx[1024 + j];
      float Hz = sScr[g8*48 + bb*12 + (1*2+jj)*2 + 1] + bhh[1024 + j];
      float In = sScr[g8*48 + bb*12 + (2*2+jj)*2 + 0] + gx[2048 + j];
      float Hn = sScr[g8*48 + bb*12 + (2*2+jj)*2 + 1] + bhh[2048 + j];
      float r = fsigm(Ir + Hr);
      float z = fsigm(Iz + Hz);
      float n = ftanh(In + r * Hn);
      hout[b*1024 + j] = (1.f - z)*n + z*h[b*1024 + j];
    }
    gridbar(bar, gen, mygen, 512);
  }
}

// ---------------- logits GEMM (bf16 MFMA) ----------------
__global__ __launch_bounds__(256) void logits_k(const u16* __restrict__ Abf,
                                                const u16* __restrict__ Wbf,
                                                const float* __restrict__ bout,
                                                float* __restrict__ out){
  __shared__ u16 As[64 * 40];
  int tid = threadIdx.x, lane = tid & 63, w = tid >> 6;
  int n0 = blockIdx.x * 64, m0 = blockIdx.y * 64;
  int lr = tid >> 2, lk = (tid & 3) * 8;
  int r16 = lane & 15, kq = lane >> 4;
  bool avalid = (m0 + lr) < 992;
  const uint4* Ap = (const uint4*)(Abf + (size_t)(m0 + lr) * 1024 + lk);
  const uint4* Wp = (const uint4*)(Wbf + (size_t)(n0 + w * 16 + r16) * 1024 + kq * 8);
  f32x4 acc0 = {0.f,0.f,0.f,0.f}, acc1 = {0.f,0.f,0.f,0.f};
  f32x4 acc2 = {0.f,0.f,0.f,0.f}, acc3 = {0.f,0.f,0.f,0.f};
  for (int k0 = 0; k0 < 1024; k0 += 32){
    uint4 a4 = avalid ? Ap[k0 >> 3] : uint4{0,0,0,0};
    uint4 b4 = Wp[k0 >> 3];
    __syncthreads();
    *(uint4*)&As[lr * 40 + lk] = a4;
    __syncthreads();
    bf16x8 bfr = __builtin_bit_cast(bf16x8, b4);
    bf16x8 a0 = __builtin_bit_cast(bf16x8, *(const uint4*)&As[( 0 + r16) * 40 + kq * 8]);
    acc0 = __builtin_amdgcn_mfma_f32_16x16x32_bf16(a0, bfr, acc0, 0, 0, 0);
    bf16x8 a1 = __builtin_bit_cast(bf16x8, *(const uint4*)&As[(16 + r16) * 40 + kq * 8]);
    acc1 = __builtin_amdgcn_mfma_f32_16x16x32_bf16(a1, bfr, acc1, 0, 0, 0);
    bf16x8 a2 = __builtin_bit_cast(bf16x8, *(const uint4*)&As[(32 + r16) * 40 + kq * 8]);
    acc2 = __builtin_amdgcn_mfma_f32_16x16x32_bf16(a2, bfr, acc2, 0, 0, 0);
    bf16x8 a3 = __builtin_bit_cast(bf16x8, *(const uint4*)&As[(48 + r16) * 40 + kq * 8]);
    acc3 = __builtin_amdgcn_mfma_f32_16x16x32_bf16(a3, bfr, acc3, 0, 0, 0);
  }
  int n = n0 + w * 16 + r16;
  float bo = bout[n];
#define STORE_MS(MS, ACC)                                                        \
  {                                                                              \
    _Pragma("unroll")                                                            \
    for (int reg = 0; reg < 4; ++reg){                                           \
      int m = m0 + MS * 16 + kq * 4 + reg;                                       \
      if (m < 992){                                                              \
        int tt = m >> 5, bb = m & 31;                                            \
        out[(size_t)(bb * 31 + tt) * 32000 + n] = ACC[reg] + bo;                 \
      }                                                                          \
    }                                                                            \
  }
  STORE_MS(0, acc0) STORE_MS(1, acc1) STORE_MS(2, acc2) STORE_MS(3, acc3)
#undef STORE_MS
}

// ---------------- row-wise log_softmax over V=32000, in-place on d_out ----------------
__global__ __launch_bounds__(256) void lsm_k(float* __restrict__ out){
  __shared__ float red[4];
  __shared__ float red2[4];
  int row = blockIdx.x, tid = threadIdx.x, w = tid >> 6;
  float* p = out + (size_t)row * 32000;
  const float4* p4 = (const float4*)p;
  float m = -1e30f;
  for (int i = tid; i < 8000; i += 256){
    float4 v = p4[i];
    m = fmaxf(m, fmaxf(fmaxf(v.x, v.y), fmaxf(v.z, v.w)));
  }
  for (int off = 32; off; off >>= 1) m = fmaxf(m, __shfl_xor(m, off));
  if ((tid & 63) == 0) red[w] = m;
  __syncthreads();
  m = fmaxf(fmaxf(red[0], red[1]), fmaxf(red[2], red[3]));
  float s = 0.f;
  for (int i = tid; i < 8000; i += 256){
    float4 v = p4[i];
    s += __expf(v.x - m) + __expf(v.y - m) + __expf(v.z - m) + __expf(v.w - m);
  }
  for (int off = 32; off; off >>= 1) s += __shfl_xor(s, off);
  if ((tid & 63) == 0) red2[w] = s;
  __syncthreads();
  s = red2[0] + red2[1] + red2[2] + red2[3];
  float lse = m + __logf(s);
  for (int i = tid; i < 8000; i += 256){
    float4 v = p4[i];
    v.x -= lse; v.y -= lse; v.z -= lse; v.w -= lse;
    ((float4*)p)[i] = v;
  }
}

extern "C" void kernel_launch(void* const* d_in, const int* in_sizes, int n_in,
                              void* d_out, int out_size, void* d_ws, size_t ws_size,
                              hipStream_t stream){
  const float* enc  = (const float*)d_in[0];
  const float* ench = (const float*)d_in[1];
  const int*   tgt  = (const int*)d_in[2];
  const float* emb  = (const float*)d_in[3];
  const float* W1   = (const float*)d_in[4];
  const float* b1   = (const float*)d_in[5];
  const float* W2   = (const float*)d_in[6];
  const float* Wih  = (const float*)d_in[7];
  const float* bih  = (const float*)d_in[8];
  const float* Whh  = (const float*)d_in[9];
  const float* bhh  = (const float*)d_in[10];
  const float* Wout = (const float*)d_in[11];
  const float* bout = (const float*)d_in[12];
  float* out = (float*)d_out;

  char* ws = (char*)d_ws;
  size_t off = 0;
  auto alloc = [&](size_t bytes)->char*{
    char* p = ws + off;
    off += (bytes + 255) & ~(size_t)255;
    return p;
  };
  float* EP   = (float*)alloc((size_t)1600 * 1024 * 4);
  float* GIX  = (float*)alloc((size_t)992 * 3072 * 4);
  float* XEMB = (float*)alloc((size_t)992 * 512 * 4);
  float* HBUF = (float*)alloc((size_t)32 * 32 * 1024 * 4);
  float* HP   = (float*)alloc((size_t)32 * 1024 * 4);
  float* CTX  = (float*)alloc((size_t)32 * 1024 * 4);
  u16*   WBF  = (u16*)alloc((size_t)32000 * 1024 * 2);
  u16*   ABF  = (u16*)alloc((size_t)992 * 1024 * 2);
  unsigned* BAR = (unsigned*)alloc(256);
  (void)ws_size; (void)in_sizes; (void)n_in; (void)out_size;

  // Phase A (parallel pre-work)
  conv_bf16_k<<<2048, 256, 0, stream>>>(Wout, WBF, 32000 * 1024 / 4);
  embed_k<<<1056, 128, 0, stream>>>(tgt, emb, ench, XEMB, HBUF);
  gemm_f32_k<<<dim3(16, 25), 256, 0, stream>>>(enc, W1, b1, EP, 1600, 1024, 1024, 2048, 1024);
  gemm_f32_k<<<dim3(48, 16), 256, 0, stream>>>(XEMB, Wih, bih, GIX, 992, 512, 512, 1536, 3072);

  // Phase B: persistent kernel (plain launch, exactly 2 blocks/CU), LDS weights
  hipMemsetAsync(BAR, 0, 256, stream);
  persist_k<<<512, 256, 0, stream>>>(enc, W1, W2, Wih, Whh, bhh,
                                     EP, GIX, HBUF, HP, CTX, BAR);

  // Phase C (deferred output projection + log_softmax)
  conv_bf16_k<<<1024, 256, 0, stream>>>(HBUF + 32768, ABF, 992 * 1024 / 4);
  logits_k<<<dim3(500, 16), 256, 0, stream>>>(ABF, WBF, bout, out);
  lsm_k<<<992, 256, 0, stream>>>(out);
}

// Round 10
// 7175.818 us; speedup vs baseline: 2.0691x; 1.0773x over previous
//
#include <hip/hip_runtime.h>
#include <stdint.h>

typedef unsigned short u16;
typedef __bf16 bf16x8 __attribute__((ext_vector_type(8)));
typedef float  f32x4  __attribute__((ext_vector_type(4)));

static __device__ __forceinline__ u16 f2bf(float x){
  uint32_t u = __float_as_uint(x);
  u += 0x7fffu + ((u >> 16) & 1u);   // RNE
  return (u16)(u >> 16);
}
static __device__ __forceinline__ float dot4(float4 a, float4 b){
  return a.x*b.x + a.y*b.y + a.z*b.z + a.w*b.w;
}
static __device__ __forceinline__ float ftanh(float x){
  float e = __expf(2.f*x);
  return 1.f - 2.f/(e + 1.f);
}
static __device__ __forceinline__ float fsigm(float x){
  return 1.f / (1.f + __expf(-x));
}

// ---------------- f32 -> bf16 convert (vectorized, grid-stride) ----------------
__global__ __launch_bounds__(256) void conv_bf16_k(const float* __restrict__ src,
                                                   u16* __restrict__ dst, int n4){
  int i = blockIdx.x * 256 + threadIdx.x;
  int stride = gridDim.x * 256;
  for (; i < n4; i += stride){
    float4 v = ((const float4*)src)[i];
    ushort4 o;
    o.x = f2bf(v.x); o.y = f2bf(v.y); o.z = f2bf(v.z); o.w = f2bf(v.w);
    ((ushort4*)dst)[i] = o;
  }
}

// ---------------- embedding gather + h0 copy ----------------
__global__ __launch_bounds__(128) void embed_k(const int* __restrict__ targets,
                                               const float* __restrict__ emb,
                                               const float* __restrict__ ench,
                                               float* __restrict__ xemb,
                                               float* __restrict__ h0){
  int blk = blockIdx.x;
  if (blk < 992){
    int t = blk >> 5, b = blk & 31;          // row m = t*32+b
    int tok = targets[b * 32 + t];
    const float4* src = (const float4*)(emb + (size_t)tok * 512);
    float4* dst = (float4*)(xemb + (size_t)blk * 512);
    dst[threadIdx.x] = src[threadIdx.x];
  } else {
    int i = (blk - 992) * 128 + threadIdx.x;
    ((float4*)h0)[i] = ((const float4*)ench)[i];
  }
}

// ---------------- generic f32 NT GEMM: C[m,n] = sum_k A[m,k]*B[n,k] + bias[n] ----------------
__global__ __launch_bounds__(256) void gemm_f32_k(const float* __restrict__ A,
                                                  const float* __restrict__ B,
                                                  const float* __restrict__ bias,
                                                  float* __restrict__ C,
                                                  int M, int K, int lda, int ldb, int ldc){
  __shared__ float As[16 * 72];
  __shared__ float Bs[16 * 72];
  int tid = threadIdx.x;
  int m0 = blockIdx.y * 64, n0 = blockIdx.x * 64;
  int tx = tid & 15, ty = tid >> 4;
  int lrow = tid >> 2, lk = (tid & 3) * 4;
  const float* Ap = A + (size_t)(m0 + lrow) * lda + lk;
  const float* Bp = B + (size_t)(n0 + lrow) * ldb + lk;
  bool avalid = (m0 + lrow) < M;
  float acc[4][4] = {};
  for (int k0 = 0; k0 < K; k0 += 16){
    float4 av = avalid ? *(const float4*)(Ap + k0) : float4{0.f,0.f,0.f,0.f};
    float4 bv = *(const float4*)(Bp + k0);
    __syncthreads();
    As[(lk+0)*72 + lrow] = av.x; As[(lk+1)*72 + lrow] = av.y;
    As[(lk+2)*72 + lrow] = av.z; As[(lk+3)*72 + lrow] = av.w;
    Bs[(lk+0)*72 + lrow] = bv.x; Bs[(lk+1)*72 + lrow] = bv.y;
    Bs[(lk+2)*72 + lrow] = bv.z; Bs[(lk+3)*72 + lrow] = bv.w;
    __syncthreads();
#pragma unroll
    for (int kk = 0; kk < 16; ++kk){
      float4 a = *(const float4*)&As[kk*72 + ty*4];
      float4 b = *(const float4*)&Bs[kk*72 + tx*4];
      float avv[4] = {a.x, a.y, a.z, a.w};
      float bvv[4] = {b.x, b.y, b.z, b.w};
#pragma unroll
      for (int i = 0; i < 4; ++i)
#pragma unroll
        for (int j = 0; j < 4; ++j)
          acc[i][j] = fmaf(avv[i], bvv[j], acc[i][j]);
    }
  }
  float4 bb = *(const float4*)(bias + n0 + tx*4);
#pragma unroll
  for (int i = 0; i < 4; ++i){
    int row = m0 + ty*4 + i;
    if (row < M){
      float4 o;
      o.x = acc[i][0] + bb.x; o.y = acc[i][1] + bb.y;
      o.z = acc[i][2] + bb.z; o.w = acc[i][3] + bb.w;
      *(float4*)(C + (size_t)row * ldc + n0 + tx*4) = o;
    }
  }
}

// ---------------- manual grid barrier, contention-free ----------------
// Arrival: ONE relaxed store to a per-block flag (no RMW -> no cacheline
// ownership serialization; 512 stores proceed in parallel).
// Wake: wave 0's 64 lanes poll 8 flags each (512 total), __all() reduce.
// Fences: one __threadfence per side, executed by a single thread (L2
// writeback/invalidate is XCD-wide; more executions are pure overhead).
static __device__ __forceinline__ void gridbar(unsigned* flags, unsigned &mygen){
  __syncthreads();
  unsigned next = mygen + 1u;
  int tid = threadIdx.x;
  if (tid == 0){
    __threadfence();   // release: write back this XCD's dirty L2 once
    __hip_atomic_store(flags + blockIdx.x, next, __ATOMIC_RELAXED,
                       __HIP_MEMORY_SCOPE_AGENT);
  }
  if (tid < 64){
    int spins = 0;
    for (;;){
      unsigned mn = 0xffffffffu;
#pragma unroll
      for (int i = 0; i < 8; ++i){
        unsigned v = __hip_atomic_load(flags + tid * 8 + i, __ATOMIC_RELAXED,
                                       __HIP_MEMORY_SCOPE_AGENT);
        mn = v < mn ? v : mn;
      }
      if (__all(mn >= next)) break;
      __builtin_amdgcn_s_sleep(1);
      if (++spins > (1 << 18)) break;   // safety valve: never hang
    }
    if (tid == 0) __threadfence();      // acquire: invalidate caches once
  }
  __syncthreads();
  mygen = next;
}

// ---------------- persistent phase-B kernel ----------------
// 512 blocks x 256 threads, exactly 2 blocks/CU (58KB static LDS, <=128 VGPR).
// Block bid owns attn-proj rows k = bid*2+{0,1} and GRU units j = bid*2+{0,1}.
// All 14 owned weight rows (56KB) live in LDS for all 31 steps.
__global__ __launch_bounds__(256, 2) void persist_k(
    const float* __restrict__ enc, const float* __restrict__ W1,
    const float* __restrict__ W2, const float* __restrict__ Wih,
    const float* __restrict__ Whh, const float* __restrict__ bhh,
    const float* __restrict__ EP, const float* __restrict__ GIX,
    float* __restrict__ HBUF, float* __restrict__ HP,
    float* __restrict__ CTX, unsigned* __restrict__ BAR){
  __shared__ float sW1h[2][1024];   // attn-proj rows (h-part of W1)
  __shared__ float sWih[6][1024];   // rr = gate*2+jj, ctx-cols of W_ih
  __shared__ float sWhh[6][1024];   // rr = gate*2+jj
  __shared__ float sScr[384];       // attn wave partials / GRU dump
  __shared__ float sA[64];
  int tid = threadIdx.x, bid = blockIdx.x;
  unsigned mygen = 0;

  // ---- one-time weight preload into LDS ----
  {
    int c = tid * 4;
#pragma unroll
    for (int kk = 0; kk < 2; ++kk)
      *(float4*)&sW1h[kk][c] =
          *(const float4*)&W1[(size_t)(bid*2 + kk)*2048 + 1024 + c];
#pragma unroll
    for (int rr = 0; rr < 6; ++rr){
      int jj = rr & 1, g = rr >> 1;
      *(float4*)&sWih[rr][c] =
          *(const float4*)&Wih[(size_t)(g*1024 + bid*2 + jj)*1536 + 512 + c];
      *(float4*)&sWhh[rr][c] =
          *(const float4*)&Whh[(size_t)(g*1024 + bid*2 + jj)*1024 + c];
    }
  }
  __syncthreads();

  int lane = tid & 31, grp = tid >> 5;   // 8 groups of 32 lanes

  for (int t = 0; t < 31; ++t){
    const float* h = HBUF + (size_t)t * 32768;
    float* hout = HBUF + (size_t)(t + 1) * 32768;

    // ---- hp[b,k] = h[b,:] . W1h[k,:]  (group grp: batches grp*4..+3) ----
    {
      float a[4][2] = {};
      for (int i = 0; i < 8; ++i){
        int f = (lane + 32*i) * 4;
        float4 w0 = *(float4*)&sW1h[0][f];
        float4 w1 = *(float4*)&sW1h[1][f];
#pragma unroll
        for (int bb = 0; bb < 4; ++bb){
          float4 hv = *(const float4*)&h[(grp*4 + bb)*1024 + f];
          a[bb][0] += dot4(hv, w0);
          a[bb][1] += dot4(hv, w1);
        }
      }
#pragma unroll
      for (int bb = 0; bb < 4; ++bb)
#pragma unroll
        for (int kk = 0; kk < 2; ++kk)
          for (int o = 1; o < 32; o <<= 1)
            a[bb][kk] += __shfl_xor(a[bb][kk], o);
      if (lane == 0){
#pragma unroll
        for (int bb = 0; bb < 4; ++bb){
          HP[(grp*4 + bb)*1024 + bid*2 + 0] = a[bb][0];
          HP[(grp*4 + bb)*1024 + bid*2 + 1] = a[bb][1];
        }
      }
    }
    gridbar(BAR, mygen);

    // ---- attention (blocks 0..31: block handles batch b = bid) ----
    if (bid < 32){
      int b = bid;
      float4 hp4 = *(const float4*)&HP[b*1024 + tid*4];
      float4 w2v = *(const float4*)&W2[tid*4];
      int lane64 = tid & 63, wv = tid >> 6;
      for (int s = 0; s < 50; ++s){
        float4 ep4 = *(const float4*)&EP[(size_t)(b*50 + s)*1024 + tid*4];
        float v = ftanh(ep4.x + hp4.x)*w2v.x + ftanh(ep4.y + hp4.y)*w2v.y
                + ftanh(ep4.z + hp4.z)*w2v.z + ftanh(ep4.w + hp4.w)*w2v.w;
        for (int o = 32; o; o >>= 1) v += __shfl_xor(v, o);
        if (lane64 == 0) sScr[s*4 + wv] = v;
      }
      __syncthreads();
      if (tid < 64){
        float e = -1e30f;
        if (tid < 50)
          e = sScr[tid*4] + sScr[tid*4+1] + sScr[tid*4+2] + sScr[tid*4+3];
        float mx = e;
        for (int o = 32; o; o >>= 1) mx = fmaxf(mx, __shfl_xor(mx, o));
        float ex = (tid < 50) ? __expf(e - mx) : 0.f;
        float sm = ex;
        for (int o = 32; o; o >>= 1) sm += __shfl_xor(sm, o);
        if (tid < 50) sA[tid] = ex / sm;
      }
      __syncthreads();
      float4 c = {0.f,0.f,0.f,0.f};
      const float* encb = enc + (size_t)b * 51200 + tid*4;
      for (int s = 0; s < 50; ++s){
        float a = sA[s];
        float4 ev = *(const float4*)&encb[s*1024];
        c.x = fmaf(a, ev.x, c.x); c.y = fmaf(a, ev.y, c.y);
        c.z = fmaf(a, ev.z, c.z); c.w = fmaf(a, ev.w, c.w);
      }
      *(float4*)&CTX[b*1024 + tid*4] = c;
    }
    gridbar(BAR, mygen);

    // ---- GRU: 2 passes (jj = 0,1), 24 accumulators each ----
#pragma unroll
    for (int jj = 0; jj < 2; ++jj){
      float aI[4][3] = {}, aH[4][3] = {};
      for (int i = 0; i < 8; ++i){
        int f = (lane + 32*i) * 4;
        float4 wI0 = *(float4*)&sWih[0*2+jj][f];
        float4 wI1 = *(float4*)&sWih[1*2+jj][f];
        float4 wI2 = *(float4*)&sWih[2*2+jj][f];
        float4 wH0 = *(float4*)&sWhh[0*2+jj][f];
        float4 wH1 = *(float4*)&sWhh[1*2+jj][f];
        float4 wH2 = *(float4*)&sWhh[2*2+jj][f];
#pragma unroll
        for (int bb = 0; bb < 4; ++bb){
          float4 cv = *(const float4*)&CTX[(grp*4 + bb)*1024 + f];
          float4 hv = *(const float4*)&h[(grp*4 + bb)*1024 + f];
          aI[bb][0] += dot4(cv, wI0); aI[bb][1] += dot4(cv, wI1); aI[bb][2] += dot4(cv, wI2);
          aH[bb][0] += dot4(hv, wH0); aH[bb][1] += dot4(hv, wH1); aH[bb][2] += dot4(hv, wH2);
        }
      }
#pragma unroll
      for (int bb = 0; bb < 4; ++bb)
#pragma unroll
        for (int g = 0; g < 3; ++g)
          for (int o = 1; o < 32; o <<= 1){
            aI[bb][g] += __shfl_xor(aI[bb][g], o);
            aH[bb][g] += __shfl_xor(aH[bb][g], o);
          }
      if (lane == 0){
#pragma unroll
        for (int bb = 0; bb < 4; ++bb)
#pragma unroll
          for (int g = 0; g < 3; ++g){
            sScr[grp*48 + bb*12 + (g*2 + jj)*2 + 0] = aI[bb][g];
            sScr[grp*48 + bb*12 + (g*2 + jj)*2 + 1] = aH[bb][g];
          }
      }
    }
    __syncthreads();
    if (tid < 64){
      int b = tid & 31, jj = tid >> 5;
      int g8 = b >> 2, bb = b & 3;
      int j = bid*2 + jj;
      const float* gx = GIX + ((size_t)t*32 + b)*3072;
      float Ir = sScr[g8*48 + bb*12 + (0*2+jj)*2 + 0] + gx[j];
      float Hr = sScr[g8*48 + bb*12 + (0*2+jj)*2 + 1] + bhh[j];
      float Iz = sScr[g8*48 + bb*12 + (1*2+jj)*2 + 0] + gx[1024 + j];
      float Hz = sScr[g8*48 + bb*12 + (1*2+jj)*2 + 1] + bhh[1024 + j];
      float In = sScr[g8*48 + bb*12 + (2*2+jj)*2 + 0] + gx[2048 + j];
      float Hn = sScr[g8*48 + bb*12 + (2*2+jj)*2 + 1] + bhh[2048 + j];
      float r = fsigm(Ir + Hr);
      float z = fsigm(Iz + Hz);
      float n = ftanh(In + r * Hn);
      hout[b*1024 + j] = (1.f - z)*n + z*h[b*1024 + j];
    }
    gridbar(BAR, mygen);
  }
}

// ---------------- logits GEMM (bf16 MFMA) ----------------
__global__ __launch_bounds__(256) void logits_k(const u16* __restrict__ Abf,
                                                const u16* __restrict__ Wbf,
                                                const float* __restrict__ bout,
                                                float* __restrict__ out){
  __shared__ u16 As[64 * 40];
  int tid = threadIdx.x, lane = tid & 63, w = tid >> 6;
  int n0 = blockIdx.x * 64, m0 = blockIdx.y * 64;
  int lr = tid >> 2, lk = (tid & 3) * 8;
  int r16 = lane & 15, kq = lane >> 4;
  bool avalid = (m0 + lr) < 992;
  const uint4* Ap = (const uint4*)(Abf + (size_t)(m0 + lr) * 1024 + lk);
  const uint4* Wp = (const uint4*)(Wbf + (size_t)(n0 + w * 16 + r16) * 1024 + kq * 8);
  f32x4 acc0 = {0.f,0.f,0.f,0.f}, acc1 = {0.f,0.f,0.f,0.f};
  f32x4 acc2 = {0.f,0.f,0.f,0.f}, acc3 = {0.f,0.f,0.f,0.f};
  for (int k0 = 0; k0 < 1024; k0 += 32){
    uint4 a4 = avalid ? Ap[k0 >> 3] : uint4{0,0,0,0};
    uint4 b4 = Wp[k0 >> 3];
    __syncthreads();
    *(uint4*)&As[lr * 40 + lk] = a4;
    __syncthreads();
    bf16x8 bfr = __builtin_bit_cast(bf16x8, b4);
    bf16x8 a0 = __builtin_bit_cast(bf16x8, *(const uint4*)&As[( 0 + r16) * 40 + kq * 8]);
    acc0 = __builtin_amdgcn_mfma_f32_16x16x32_bf16(a0, bfr, acc0, 0, 0, 0);
    bf16x8 a1 = __builtin_bit_cast(bf16x8, *(const uint4*)&As[(16 + r16) * 40 + kq * 8]);
    acc1 = __builtin_amdgcn_mfma_f32_16x16x32_bf16(a1, bfr, acc1, 0, 0, 0);
    bf16x8 a2 = __builtin_bit_cast(bf16x8, *(const uint4*)&As[(32 + r16) * 40 + kq * 8]);
    acc2 = __builtin_amdgcn_mfma_f32_16x16x32_bf16(a2, bfr, acc2, 0, 0, 0);
    bf16x8 a3 = __builtin_bit_cast(bf16x8, *(const uint4*)&As[(48 + r16) * 40 + kq * 8]);
    acc3 = __builtin_amdgcn_mfma_f32_16x16x32_bf16(a3, bfr, acc3, 0, 0, 0);
  }
  int n = n0 + w * 16 + r16;
  float bo = bout[n];
#define STORE_MS(MS, ACC)                                                        \
  {                                                                              \
    _Pragma("unroll")                                                            \
    for (int reg = 0; reg < 4; ++reg){                                           \
      int m = m0 + MS * 16 + kq * 4 + reg;                                       \
      if (m < 992){                                                              \
        int tt = m >> 5, bb = m & 31;                                            \
        out[(size_t)(bb * 31 + tt) * 32000 + n] = ACC[reg] + bo;                 \
      }                                                                          \
    }                                                                            \
  }
  STORE_MS(0, acc0) STORE_MS(1, acc1) STORE_MS(2, acc2) STORE_MS(3, acc3)
#undef STORE_MS
}

// ---------------- row-wise log_softmax over V=32000, in-place on d_out ----------------
__global__ __launch_bounds__(256) void lsm_k(float* __restrict__ out){
  __shared__ float red[4];
  __shared__ float red2[4];
  int row = blockIdx.x, tid = threadIdx.x, w = tid >> 6;
  float* p = out + (size_t)row * 32000;
  const float4* p4 = (const float4*)p;
  float m = -1e30f;
  for (int i = tid; i < 8000; i += 256){
    float4 v = p4[i];
    m = fmaxf(m, fmaxf(fmaxf(v.x, v.y), fmaxf(v.z, v.w)));
  }
  for (int off = 32; off; off >>= 1) m = fmaxf(m, __shfl_xor(m, off));
  if ((tid & 63) == 0) red[w] = m;
  __syncthreads();
  m = fmaxf(fmaxf(red[0], red[1]), fmaxf(red[2], red[3]));
  float s = 0.f;
  for (int i = tid; i < 8000; i += 256){
    float4 v = p4[i];
    s += __expf(v.x - m) + __expf(v.y - m) + __expf(v.z - m) + __expf(v.w - m);
  }
  for (int off = 32; off; off >>= 1) s += __shfl_xor(s, off);
  if ((tid & 63) == 0) red2[w] = s;
  __syncthreads();
  s = red2[0] + red2[1] + red2[2] + red2[3];
  float lse = m + __logf(s);
  for (int i = tid; i < 8000; i += 256){
    float4 v = p4[i];
    v.x -= lse; v.y -= lse; v.z -= lse; v.w -= lse;
    ((float4*)p)[i] = v;
  }
}

extern "C" void kernel_launch(void* const* d_in, const int* in_sizes, int n_in,
                              void* d_out, int out_size, void* d_ws, size_t ws_size,
                              hipStream_t stream){
  const float* enc  = (const float*)d_in[0];
  const float* ench = (const float*)d_in[1];
  const int*   tgt  = (const int*)d_in[2];
  const float* emb  = (const float*)d_in[3];
  const float* W1   = (const float*)d_in[4];
  const float* b1   = (const float*)d_in[5];
  const float* W2   = (const float*)d_in[6];
  const float* Wih  = (const float*)d_in[7];
  const float* bih  = (const float*)d_in[8];
  const float* Whh  = (const float*)d_in[9];
  const float* bhh  = (const float*)d_in[10];
  const float* Wout = (const float*)d_in[11];
  const float* bout = (const float*)d_in[12];
  float* out = (float*)d_out;

  char* ws = (char*)d_ws;
  size_t off = 0;
  auto alloc = [&](size_t bytes)->char*{
    char* p = ws + off;
    off += (bytes + 255) & ~(size_t)255;
    return p;
  };
  float* EP   = (float*)alloc((size_t)1600 * 1024 * 4);
  float* GIX  = (float*)alloc((size_t)992 * 3072 * 4);
  float* XEMB = (float*)alloc((size_t)992 * 512 * 4);
  float* HBUF = (float*)alloc((size_t)32 * 32 * 1024 * 4);
  float* HP   = (float*)alloc((size_t)32 * 1024 * 4);
  float* CTX  = (float*)alloc((size_t)32 * 1024 * 4);
  u16*   WBF  = (u16*)alloc((size_t)32000 * 1024 * 2);
  u16*   ABF  = (u16*)alloc((size_t)992 * 1024 * 2);
  unsigned* BAR = (unsigned*)alloc(512 * 4);   // one flag per block
  (void)ws_size; (void)in_sizes; (void)n_in; (void)out_size;

  // Phase A (parallel pre-work)
  conv_bf16_k<<<2048, 256, 0, stream>>>(Wout, WBF, 32000 * 1024 / 4);
  embed_k<<<1056, 128, 0, stream>>>(tgt, emb, ench, XEMB, HBUF);
  gemm_f32_k<<<dim3(16, 25), 256, 0, stream>>>(enc, W1, b1, EP, 1600, 1024, 1024, 2048, 1024);
  gemm_f32_k<<<dim3(48, 16), 256, 0, stream>>>(XEMB, Wih, bih, GIX, 992, 512, 512, 1536, 3072);

  // Phase B: persistent kernel (plain launch, exactly 2 blocks/CU), LDS weights
  hipMemsetAsync(BAR, 0, 512 * 4, stream);
  persist_k<<<512, 256, 0, stream>>>(enc, W1, W2, Wih, Whh, bhh,
                                     EP, GIX, HBUF, HP, CTX, BAR);

  // Phase C (deferred output projection + log_softmax)
  conv_bf16_k<<<1024, 256, 0, stream>>>(HBUF + 32768, ABF, 992 * 1024 / 4);
  logits_k<<<dim3(500, 16), 256, 0, stream>>>(ABF, WBF, bout, out);
  lsm_k<<<992, 256, 0, stream>>>(out);
}